// Round 3
// baseline (140.553 us; speedup 1.0000x reference)
//
#include <hip/hip_runtime.h>
#include <hip/hip_bf16.h>
#include <stdint.h>

// Problem constants (fixed by setup_inputs)
#define M_N  16384   // batch rows
#define K_C  2048    // centers
#define DIM  512     // feature dim
#define NCLS 10      // classes
#define NBN  16      // center-blocks (K_C/128) -> split-K partials
#define NBM  (M_N / 128)   // 128 bm slices

typedef unsigned short u16;
typedef float  f32x4  __attribute__((ext_vector_type(4)));
typedef __bf16 bf16x8 __attribute__((ext_vector_type(8)));

#define SB0 __builtin_amdgcn_sched_barrier(0)

// ---- helpers -------------------------------------------------------------

__device__ __forceinline__ void async_ld16(const void* g, void* l) {
  // global -> LDS direct DMA, 16 bytes per lane. LDS dest is wave-uniform
  // base + lane*16 -- swizzle must be on the SOURCE.
  __builtin_amdgcn_global_load_lds(
      (const __attribute__((address_space(1))) void*)g,
      (__attribute__((address_space(3))) void*)l,
      16, 0, 0);
}

__device__ __forceinline__ u16 f2bf_rne(float f) {
  uint32_t u = __float_as_uint(f);
  u += 0x7FFFu + ((u >> 16) & 1u);
  return (u16)(u >> 16);
}

// ---- kernel 1: prep (batches/centers -> bf16 + norms, W -> Wperm bf16) ---
// Verbatim from the 136.5us session kernel.

#define NPREP ((M_N + K_C) / 2)

__global__ __launch_bounds__(256) void prep(
    const float4* __restrict__ batches, const float4* __restrict__ centers,
    const float* __restrict__ W,
    ushort4* __restrict__ Abf, ushort4* __restrict__ Bbf,
    float* __restrict__ x2, float* __restrict__ c2, u16* __restrict__ Wperm) {
  int b = blockIdx.x, t = threadIdx.x;
  if (b < NPREP) {
    int rp = b * 2 + (t >> 7);          // row index (pair)
    int col = t & 127;
    const float4* src; ushort4* dst; float* sq; int row;
    if (rp < M_N) { src = batches; dst = Abf; sq = x2; row = rp; }
    else          { src = centers; dst = Bbf; sq = c2; row = rp - M_N; }
    float4 v = src[(size_t)row * 128 + col];
    float ss = v.x * v.x + v.y * v.y + v.z * v.z + v.w * v.w;
    ushort4 o;
    o.x = f2bf_rne(v.x); o.y = f2bf_rne(v.y);
    o.z = f2bf_rne(v.z); o.w = f2bf_rne(v.w);
    dst[(size_t)row * 128 + col] = o;
    ss += __shfl_down(ss, 32);
    ss += __shfl_down(ss, 16);
    ss += __shfl_down(ss, 8);
    ss += __shfl_down(ss, 4);
    ss += __shfl_down(ss, 2);
    ss += __shfl_down(ss, 1);
    __shared__ float part[4];
    if ((t & 63) == 0) part[t >> 6] = ss;
    __syncthreads();
    if (t == 0) sq[row] = part[0] + part[1];
    if (t == 128) sq[row] = part[2] + part[3];
  } else {
    int wb = b - NPREP;                 // 32 blocks x 1024 elems
#pragma unroll
    for (int i = 0; i < 4; ++i) {
      int p = wb * 1024 + i * 256 + t;  // < 16*2048
      int cls = p >> 11, k = p & 2047;
      int bn = k >> 7, rem = k & 127;
      int hh = (rem >> 6) & 1, tt = (rem >> 5) & 1;
      int qq = (rem >> 3) & 3, jj = rem & 7;
      int c = bn * 128 + hh * 64 + (tt * 2 + (jj >> 2)) * 16 + qq * 4 + (jj & 3);
      Wperm[p] = (cls < NCLS) ? f2bf_rne(W[cls * K_C + c]) : (u16)0;
    }
  }
}

// ---- kernel 2: fused xc-GEMM -> radial -> MFMA (radial@Wperm^T) ----------
//
// Round-0 geometry (128x128 tile, 4 waves 2x2, 32 KiB LDS, 4 blocks/CU)
// with the K-loop restructured from "sync; stage; sync(vmcnt0); compute"
// to the T3-minimum counted-vmcnt pipeline:
//
//   BK=32, double-buffered within the SAME 32 KiB. Buffer layout per
//   parity p = t&1 (16 KiB each): CENTERS at p*16384 + [0,8192),
//   BATCHES at p*16384 + 8192 + [0,8192)  (matches read convention:
//   cf = centers = FIRST operand from low region).
//   per step t: ds_read buf[t&1]; lgkmcnt(0); barrier;   (reads retired)
//               STAGE(t+2) -> buf[t&1];                  (overwrites safe)
//               16 MFMA (setprio);                       (loads fly under MFMA)
//               vmcnt(4); barrier;                       (t+1 landed; t+2 in flight)
//   vmcnt never drains to 0 mid-loop; 4 independent blocks/CU overlap
//   each other's LDS/MFMA/stage phases as in round-0.
// R2 BUG FIXED HERE: R2 staged batches into the low region while reads
// expected centers there (operand transpose -> absmax 2e-2). Staging
// destinations are now swapped back to match the reads.

__global__ __launch_bounds__(256, 4) void rbf_main(
    const u16* __restrict__ A,      // bf16 bits [M_N][DIM]  (batches)
    const u16* __restrict__ B,      // bf16 bits [K_C][DIM]  (centers)
    const float* __restrict__ x2,   // [M_N]
    const float* __restrict__ c2,   // [K_C]
    const float* __restrict__ beta, // [K_C]
    const u16* __restrict__ Wperm,  // bf16 bits [16][K_C] permuted
    float* __restrict__ partial) {  // [NBN][M_N][16]
  constexpr int BK = 32;
  constexpr int NST = DIM / BK;     // 16
  __shared__ alignas(16) unsigned char smem[32768];
  f32x4* sumbuf = (f32x4*)smem;     // 8 KB wave-pair sum (after K-loop)

  const int tid  = threadIdx.x;
  const int lane = tid & 63;
  const int wid  = tid >> 6;
  const int bid = blockIdx.x;
  const int g = bid >> 3, r8 = bid & 7;
  const int bm = r8 * 16 + (g & 15);
  const int bn = g >> 4;
  const int row0 = bm * 128, col0 = bn * 128;
  const int wrC = (wid >> 1) * 64;   // wave CENTER offset in tile
  const int wcB = (wid & 1) * 64;    // wave BATCH offset in tile

  f32x4 acc[4][4] = {};   // acc[mi = center strip][ni = batch strip]

  // staging: thread t -> LDS (row = t>>2 [+64j], slot = t&3); source chunk
  // pre-swizzled: LDS[r][slot] = global[r][slot ^ (r&3)].
  const int srow = tid >> 2;          // 0..63
  const int sgch = (tid & 3) ^ (srow & 3);
  const u16* aG = A + (size_t)(row0 + srow) * DIM + sgch * 8;  // batches
  const u16* bG = B + (size_t)(col0 + srow) * DIM + sgch * 8;  // centers

  // CENTERS -> low 8 KiB, BATCHES -> high 8 KiB of each parity buffer.
#define STAGE(tt) do { \
    _Pragma("unroll") for (int j = 0; j < 2; ++j) { \
      async_ld16(bG + (size_t)j * 64 * DIM + (tt) * BK, \
                 smem + ((tt) & 1) * 16384 + j * 4096 + tid * 16); \
      async_ld16(aG + (size_t)j * 64 * DIM + (tt) * BK, \
                 smem + ((tt) & 1) * 16384 + 8192 + j * 4096 + tid * 16); \
    } \
  } while (0)

  // MFMA operand addressing: row frow within 16-strip, k-chunk fq (8 bf16),
  // swizzled slot = fq ^ (row & 3).
  const int frow = lane & 15;
  const int fq   = lane >> 4;
  const int slotB = ((fq ^ (frow & 3)) * 16);   // byte offset of 16B chunk

  // ---- prologue: stage steps 0,1; wait step 0 landed (4 newest in flight)
  STAGE(0); STAGE(1);
  asm volatile("s_waitcnt vmcnt(4)" ::: "memory");
  __builtin_amdgcn_s_barrier();
  SB0;

#pragma unroll
  for (int t = 0; t < NST; ++t) {
    const unsigned char* base = smem + (t & 1) * 16384;
    bf16x8 cf[4], bfr[4];
#pragma unroll
    for (int mi = 0; mi < 4; ++mi)   // centers = FIRST operand (low region)
      cf[mi] = *(const bf16x8*)(base + (wrC + mi * 16 + frow) * 64 + slotB);
#pragma unroll
    for (int ni = 0; ni < 4; ++ni)   // batches = SECOND operand (high region)
      bfr[ni] = *(const bf16x8*)(base + 8192 + (wcB + ni * 16 + frow) * 64 + slotB);
    asm volatile("s_waitcnt lgkmcnt(0)" ::: "memory");
    SB0;                             // rule 18: no MFMA hoists above lgkm
    __builtin_amdgcn_s_barrier();    // all waves' reads of buf[t&1] retired
    SB0;

    if (t < NST - 2) STAGE(t + 2);   // overwrite buf[t&1]; flies under MFMA

    __builtin_amdgcn_s_setprio(1);
#pragma unroll
    for (int mi = 0; mi < 4; ++mi)
#pragma unroll
      for (int ni = 0; ni < 4; ++ni)
        acc[mi][ni] = __builtin_amdgcn_mfma_f32_16x16x32_bf16(
            cf[mi], bfr[ni], acc[mi][ni], 0, 0, 0);
    __builtin_amdgcn_s_setprio(0);
    SB0;

    if (t < NST - 2) {
      asm volatile("s_waitcnt vmcnt(4)" ::: "memory");  // t+1 landed
    } else if (t == NST - 2) {
      asm volatile("s_waitcnt vmcnt(0)" ::: "memory");  // last buffer landed
    }
    __builtin_amdgcn_s_barrier();
    SB0;
  }

  // ---- epilogue: acc (xc) -> radial, IN PLACE ----
  // D layout: col(lane&15)=batch within 16-strip, row(q*4+reg)=center.
  const int cls = lane & 15, q = lane >> 4;
  float4 c2q[4], btq[4];
#pragma unroll
  for (int mi = 0; mi < 4; ++mi) {
    int base2 = col0 + wrC + mi * 16 + q * 4;   // 4 consecutive centers
    c2q[mi] = *(const float4*)(c2 + base2);
    btq[mi] = *(const float4*)(beta + base2);
  }
  float x2v[4];
#pragma unroll
  for (int ni = 0; ni < 4; ++ni)
    x2v[ni] = x2[row0 + wcB + ni * 16 + cls];

#pragma unroll
  for (int mi = 0; mi < 4; ++mi)
#pragma unroll
    for (int ni = 0; ni < 4; ++ni)
#pragma unroll
      for (int r = 0; r < 4; ++r) {
        float xc = acc[mi][ni][r];
        float d2 = fmaxf(x2v[ni] + c2q[mi][r] - 2.0f * xc, 0.0f);
        acc[mi][ni][r] = __expf(-btq[mi][r] * sqrtf(d2));
      }

  // ---- stage 2: this wave's 64-center half vs its Wperm half ----
  const int h = wid >> 1;            // which 64-center half
  bf16x8 wfr[2];
#pragma unroll
  for (int t = 0; t < 2; ++t)
    wfr[t] = *(const bf16x8*)(Wperm + (size_t)cls * K_C + col0 + h * 64 +
                              t * 32 + q * 8);

  f32x4 acc2[4] = {};
#pragma unroll
  for (int ni = 0; ni < 4; ++ni) {
#pragma unroll
    for (int t = 0; t < 2; ++t) {
      union { u16 hh[8]; bf16x8 v; } pk;
#pragma unroll
      for (int r = 0; r < 4; ++r) {
        pk.hh[r]     = f2bf_rne(acc[2 * t][ni][r]);
        pk.hh[4 + r] = f2bf_rne(acc[2 * t + 1][ni][r]);
      }
      acc2[ni] = __builtin_amdgcn_mfma_f32_16x16x32_bf16(
          pk.v, wfr[t], acc2[ni], 0, 0, 0);
    }
  }

  // ---- wave-pair sum (wid and wid+2 share batches, split centers) ----
  __syncthreads();   // staging LDS dead; reuse as sumbuf
  if (wid >= 2) {
#pragma unroll
    for (int ni = 0; ni < 4; ++ni)
      sumbuf[((wid & 1) * 4 + ni) * 64 + lane] = acc2[ni];
  }
  __syncthreads();
  if (wid < 2) {
#pragma unroll
    for (int ni = 0; ni < 4; ++ni) {
      f32x4 o = sumbuf[(wid * 4 + ni) * 64 + lane];
      acc2[ni] += o;
      // D2: col(lane&15)=class, row(q*4+r)=batch row within strip.
#pragma unroll
      for (int r = 0; r < 4; ++r) {
        int gr = row0 + wid * 64 + ni * 16 + q * 4 + r;
        __builtin_nontemporal_store(
            acc2[ni][r], &partial[((size_t)bn * M_N + gr) * 16 + cls]);
      }
    }
  }
#undef STAGE
}

// ---- kernel 3: out[i][:] = b + sum_bn partial[bn][i][:] ------------------

__global__ __launch_bounds__(256) void reduce_out(
    const float* __restrict__ partial, const float* __restrict__ b,
    float* __restrict__ out) {
  int t = threadIdx.x;
  int row = blockIdx.x * 64 + (t >> 2);
  int quad = t & 3;
  f32x4 v = {0.f, 0.f, 0.f, 0.f};
#pragma unroll
  for (int bn = 0; bn < NBN; ++bn) {
    f32x4 p = __builtin_nontemporal_load(
        (const f32x4*)(partial + ((size_t)bn * M_N + row) * 16 + quad * 4));
    v += p;
  }
  if (quad == 0) {
    float4 bq = *(const float4*)b;
    float* o = out + (size_t)row * NCLS;
    *(float2*)o       = {v.x + bq.x, v.y + bq.y};
    *(float2*)(o + 2) = {v.z + bq.z, v.w + bq.w};
  } else if (quad == 1) {
    float4 bq = *(const float4*)(b + 4);
    float* o = out + (size_t)row * NCLS + 4;
    *(float2*)o       = {v.x + bq.x, v.y + bq.y};
    *(float2*)(o + 2) = {v.z + bq.z, v.w + bq.w};
  } else if (quad == 2) {
    *(float2*)(out + (size_t)row * NCLS + 8) = {v.x + b[8], v.y + b[9]};
  }
}

// ---- launch --------------------------------------------------------------

extern "C" void kernel_launch(void* const* d_in, const int* in_sizes, int n_in,
                              void* d_out, int out_size, void* d_ws, size_t ws_size,
                              hipStream_t stream) {
  const float* batches = (const float*)d_in[0];  // [16384,512]
  const float* centers = (const float*)d_in[1];  // [2048,512]
  const float* beta    = (const float*)d_in[2];  // [1,2048]
  const float* W       = (const float*)d_in[3];  // [10,2048]
  const float* bias    = (const float*)d_in[4];  // [10]
  float* out = (float*)d_out;                    // [16384,10]

  char* ws = (char*)d_ws;
  u16*  Abf = (u16*)ws;                                   // 16 MiB
  u16*  Bbf = (u16*)(ws + (size_t)M_N * DIM * 2);         // 2 MiB
  float* x2 = (float*)(ws + (size_t)(M_N + K_C) * DIM * 2);
  float* c2 = x2 + M_N;
  u16*  Wpm = (u16*)(c2 + K_C);                           // 64 KiB
  float* partial = (float*)((char*)Wpm + 16 * K_C * 2);   // 16.8 MiB

  prep<<<dim3(NPREP + 32), dim3(256), 0, stream>>>(
      (const float4*)batches, (const float4*)centers, W,
      (ushort4*)Abf, (ushort4*)Bbf, x2, c2, Wpm);
  rbf_main<<<dim3(NBN * NBM), dim3(256), 0, stream>>>(
      Abf, Bbf, x2, c2, beta, Wpm, partial);
  reduce_out<<<dim3(M_N / 64), dim3(256), 0, stream>>>(partial, bias, out);
}

// Round 4
// 139.020 us; speedup vs baseline: 1.0110x; 1.0110x over previous
//
#include <hip/hip_runtime.h>
#include <hip/hip_bf16.h>
#include <stdint.h>

// Problem constants (fixed by setup_inputs)
#define M_N  16384   // batch rows
#define K_C  2048    // centers
#define DIM  512     // feature dim
#define NCLS 10      // classes
#define NBN  16      // center-blocks (K_C/128) -> split-K partials
#define NBM  (M_N / 128)   // 128 bm slices

typedef unsigned short u16;
typedef float  f32x4  __attribute__((ext_vector_type(4)));
typedef __bf16 bf16x8 __attribute__((ext_vector_type(8)));

#define SB0 __builtin_amdgcn_sched_barrier(0)

// ---- helpers -------------------------------------------------------------

__device__ __forceinline__ void async_ld16(const void* g, void* l) {
  // global -> LDS direct DMA, 16 bytes per lane. LDS dest is wave-uniform
  // base + lane*16 -- swizzle must be on the SOURCE.
  __builtin_amdgcn_global_load_lds(
      (const __attribute__((address_space(1))) void*)g,
      (__attribute__((address_space(3))) void*)l,
      16, 0, 0);
}

__device__ __forceinline__ u16 f2bf_rne(float f) {
  uint32_t u = __float_as_uint(f);
  u += 0x7FFFu + ((u >> 16) & 1u);
  return (u16)(u >> 16);
}

// ---- kernel 1: prep (batches/centers -> bf16 + norms, W -> Wperm bf16) ---
// Verbatim from the 136.5us session kernel.

#define NPREP ((M_N + K_C) / 2)

__global__ __launch_bounds__(256) void prep(
    const float4* __restrict__ batches, const float4* __restrict__ centers,
    const float* __restrict__ W,
    ushort4* __restrict__ Abf, ushort4* __restrict__ Bbf,
    float* __restrict__ x2, float* __restrict__ c2, u16* __restrict__ Wperm) {
  int b = blockIdx.x, t = threadIdx.x;
  if (b < NPREP) {
    int rp = b * 2 + (t >> 7);          // row index (pair)
    int col = t & 127;
    const float4* src; ushort4* dst; float* sq; int row;
    if (rp < M_N) { src = batches; dst = Abf; sq = x2; row = rp; }
    else          { src = centers; dst = Bbf; sq = c2; row = rp - M_N; }
    float4 v = src[(size_t)row * 128 + col];
    float ss = v.x * v.x + v.y * v.y + v.z * v.z + v.w * v.w;
    ushort4 o;
    o.x = f2bf_rne(v.x); o.y = f2bf_rne(v.y);
    o.z = f2bf_rne(v.z); o.w = f2bf_rne(v.w);
    dst[(size_t)row * 128 + col] = o;
    ss += __shfl_down(ss, 32);
    ss += __shfl_down(ss, 16);
    ss += __shfl_down(ss, 8);
    ss += __shfl_down(ss, 4);
    ss += __shfl_down(ss, 2);
    ss += __shfl_down(ss, 1);
    __shared__ float part[4];
    if ((t & 63) == 0) part[t >> 6] = ss;
    __syncthreads();
    if (t == 0) sq[row] = part[0] + part[1];
    if (t == 128) sq[row] = part[2] + part[3];
  } else {
    int wb = b - NPREP;                 // 32 blocks x 1024 elems
#pragma unroll
    for (int i = 0; i < 4; ++i) {
      int p = wb * 1024 + i * 256 + t;  // < 16*2048
      int cls = p >> 11, k = p & 2047;
      int bn = k >> 7, rem = k & 127;
      int hh = (rem >> 6) & 1, tt = (rem >> 5) & 1;
      int qq = (rem >> 3) & 3, jj = rem & 7;
      int c = bn * 128 + hh * 64 + (tt * 2 + (jj >> 2)) * 16 + qq * 4 + (jj & 3);
      Wperm[p] = (cls < NCLS) ? f2bf_rne(W[cls * K_C + c]) : (u16)0;
    }
  }
}

// ---- kernel 2: fused xc-GEMM -> radial -> MFMA (radial@Wperm^T) ----------
//
// R3 structure (counted-vmcnt BK=32 double-buffer in 32 KiB, 4 blocks/CU)
// with the bank-conflict bug fixed:
//
// R3 used swizzle key (row & 3). With 64 B rows, lanes sharing frow&1 hit
// only 2 of the 4 16-B chunk slots -> 4-way ds_read_b128 conflict (4.19M
// conflict-cycles, ~+5 us). Fixed key = ((row >> 1) & 3): for fixed fq the
// 16 frow lanes map 2-per-slot across all 8 bank slots -> 2-way = free.
// Key is strip-invariant (strips are multiples of 16; 16>>1 = 8 == 0 mod 4)
// and j-invariant on the staging side (64>>1 = 32 == 0 mod 4).
//
// Layout per parity p = t&1 (16 KiB): CENTERS at p*16384 + [0,8192),
// BATCHES at p*16384 + 8192 + [0,8192).
//   per step t: ds_read buf[t&1]; lgkmcnt(0); barrier;
//               STAGE(t+2) -> buf[t&1];
//               16 MFMA (setprio);
//               vmcnt(4); barrier;        (t+1 landed; t+2 in flight)

__global__ __launch_bounds__(256, 4) void rbf_main(
    const u16* __restrict__ A,      // bf16 bits [M_N][DIM]  (batches)
    const u16* __restrict__ B,      // bf16 bits [K_C][DIM]  (centers)
    const float* __restrict__ x2,   // [M_N]
    const float* __restrict__ c2,   // [K_C]
    const float* __restrict__ beta, // [K_C]
    const u16* __restrict__ Wperm,  // bf16 bits [16][K_C] permuted
    float* __restrict__ partial) {  // [NBN][M_N][16]
  constexpr int BK = 32;
  constexpr int NST = DIM / BK;     // 16
  __shared__ alignas(16) unsigned char smem[32768];
  f32x4* sumbuf = (f32x4*)smem;     // 8 KB wave-pair sum (after K-loop)

  const int tid  = threadIdx.x;
  const int lane = tid & 63;
  const int wid  = tid >> 6;
  const int bid = blockIdx.x;
  const int g = bid >> 3, r8 = bid & 7;
  const int bm = r8 * 16 + (g & 15);
  const int bn = g >> 4;
  const int row0 = bm * 128, col0 = bn * 128;
  const int wrC = (wid >> 1) * 64;   // wave CENTER offset in tile
  const int wcB = (wid & 1) * 64;    // wave BATCH offset in tile

  f32x4 acc[4][4] = {};   // acc[mi = center strip][ni = batch strip]

  // staging: thread t -> LDS (row = t>>2 [+64j], slot = t&3); source chunk
  // pre-swizzled: LDS[r][slot] = global[r][slot ^ ((r>>1)&3)].
  const int srow = tid >> 2;          // 0..63
  const int sgch = (tid & 3) ^ ((srow >> 1) & 3);
  const u16* aG = A + (size_t)(row0 + srow) * DIM + sgch * 8;  // batches
  const u16* bG = B + (size_t)(col0 + srow) * DIM + sgch * 8;  // centers

  // CENTERS -> low 8 KiB, BATCHES -> high 8 KiB of each parity buffer.
#define STAGE(tt) do { \
    _Pragma("unroll") for (int j = 0; j < 2; ++j) { \
      async_ld16(bG + (size_t)j * 64 * DIM + (tt) * BK, \
                 smem + ((tt) & 1) * 16384 + j * 4096 + tid * 16); \
      async_ld16(aG + (size_t)j * 64 * DIM + (tt) * BK, \
                 smem + ((tt) & 1) * 16384 + 8192 + j * 4096 + tid * 16); \
    } \
  } while (0)

  // MFMA operand addressing: row frow within 16-strip, k-chunk fq (8 bf16),
  // swizzled slot = fq ^ ((frow>>1) & 3).
  const int frow = lane & 15;
  const int fq   = lane >> 4;
  const int slotB = ((fq ^ ((frow >> 1) & 3)) * 16);   // byte offset

  // ---- prologue: stage steps 0,1; wait step 0 landed (4 newest in flight)
  STAGE(0); STAGE(1);
  asm volatile("s_waitcnt vmcnt(4)" ::: "memory");
  __builtin_amdgcn_s_barrier();
  SB0;

#pragma unroll
  for (int t = 0; t < NST; ++t) {
    const unsigned char* base = smem + (t & 1) * 16384;
    bf16x8 cf[4], bfr[4];
#pragma unroll
    for (int mi = 0; mi < 4; ++mi)   // centers = FIRST operand (low region)
      cf[mi] = *(const bf16x8*)(base + (wrC + mi * 16 + frow) * 64 + slotB);
#pragma unroll
    for (int ni = 0; ni < 4; ++ni)   // batches = SECOND operand (high region)
      bfr[ni] = *(const bf16x8*)(base + 8192 + (wcB + ni * 16 + frow) * 64 + slotB);
    asm volatile("s_waitcnt lgkmcnt(0)" ::: "memory");
    SB0;                             // rule 18: no MFMA hoists above lgkm
    __builtin_amdgcn_s_barrier();    // all waves' reads of buf[t&1] retired
    SB0;

    if (t < NST - 2) STAGE(t + 2);   // overwrite buf[t&1]; flies under MFMA

    __builtin_amdgcn_s_setprio(1);
#pragma unroll
    for (int mi = 0; mi < 4; ++mi)
#pragma unroll
      for (int ni = 0; ni < 4; ++ni)
        acc[mi][ni] = __builtin_amdgcn_mfma_f32_16x16x32_bf16(
            cf[mi], bfr[ni], acc[mi][ni], 0, 0, 0);
    __builtin_amdgcn_s_setprio(0);
    SB0;

    if (t < NST - 2) {
      asm volatile("s_waitcnt vmcnt(4)" ::: "memory");  // t+1 landed
    } else if (t == NST - 2) {
      asm volatile("s_waitcnt vmcnt(0)" ::: "memory");  // last buffer landed
    }
    __builtin_amdgcn_s_barrier();
    SB0;
  }

  // ---- epilogue: acc (xc) -> radial, IN PLACE ----
  // D layout: col(lane&15)=batch within 16-strip, row(q*4+reg)=center.
  const int cls = lane & 15, q = lane >> 4;
  float4 c2q[4], btq[4];
#pragma unroll
  for (int mi = 0; mi < 4; ++mi) {
    int base2 = col0 + wrC + mi * 16 + q * 4;   // 4 consecutive centers
    c2q[mi] = *(const float4*)(c2 + base2);
    btq[mi] = *(const float4*)(beta + base2);
  }
  float x2v[4];
#pragma unroll
  for (int ni = 0; ni < 4; ++ni)
    x2v[ni] = x2[row0 + wcB + ni * 16 + cls];

#pragma unroll
  for (int mi = 0; mi < 4; ++mi)
#pragma unroll
    for (int ni = 0; ni < 4; ++ni)
#pragma unroll
      for (int r = 0; r < 4; ++r) {
        float xc = acc[mi][ni][r];
        float d2 = fmaxf(x2v[ni] + c2q[mi][r] - 2.0f * xc, 0.0f);
        acc[mi][ni][r] = __expf(-btq[mi][r] * sqrtf(d2));
      }

  // ---- stage 2: this wave's 64-center half vs its Wperm half ----
  const int h = wid >> 1;            // which 64-center half
  bf16x8 wfr[2];
#pragma unroll
  for (int t = 0; t < 2; ++t)
    wfr[t] = *(const bf16x8*)(Wperm + (size_t)cls * K_C + col0 + h * 64 +
                              t * 32 + q * 8);

  f32x4 acc2[4] = {};
#pragma unroll
  for (int ni = 0; ni < 4; ++ni) {
#pragma unroll
    for (int t = 0; t < 2; ++t) {
      union { u16 hh[8]; bf16x8 v; } pk;
#pragma unroll
      for (int r = 0; r < 4; ++r) {
        pk.hh[r]     = f2bf_rne(acc[2 * t][ni][r]);
        pk.hh[4 + r] = f2bf_rne(acc[2 * t + 1][ni][r]);
      }
      acc2[ni] = __builtin_amdgcn_mfma_f32_16x16x32_bf16(
          pk.v, wfr[t], acc2[ni], 0, 0, 0);
    }
  }

  // ---- wave-pair sum (wid and wid+2 share batches, split centers) ----
  __syncthreads();   // staging LDS dead; reuse as sumbuf
  if (wid >= 2) {
#pragma unroll
    for (int ni = 0; ni < 4; ++ni)
      sumbuf[((wid & 1) * 4 + ni) * 64 + lane] = acc2[ni];
  }
  __syncthreads();
  if (wid < 2) {
#pragma unroll
    for (int ni = 0; ni < 4; ++ni) {
      f32x4 o = sumbuf[(wid * 4 + ni) * 64 + lane];
      acc2[ni] += o;
      // D2: col(lane&15)=class, row(q*4+r)=batch row within strip.
#pragma unroll
      for (int r = 0; r < 4; ++r) {
        int gr = row0 + wid * 64 + ni * 16 + q * 4 + r;
        __builtin_nontemporal_store(
            acc2[ni][r], &partial[((size_t)bn * M_N + gr) * 16 + cls]);
      }
    }
  }
#undef STAGE
}

// ---- kernel 3: out[i][:] = b + sum_bn partial[bn][i][:] ------------------

__global__ __launch_bounds__(256) void reduce_out(
    const float* __restrict__ partial, const float* __restrict__ b,
    float* __restrict__ out) {
  int t = threadIdx.x;
  int row = blockIdx.x * 64 + (t >> 2);
  int quad = t & 3;
  f32x4 v = {0.f, 0.f, 0.f, 0.f};
#pragma unroll
  for (int bn = 0; bn < NBN; ++bn) {
    f32x4 p = __builtin_nontemporal_load(
        (const f32x4*)(partial + ((size_t)bn * M_N + row) * 16 + quad * 4));
    v += p;
  }
  if (quad == 0) {
    float4 bq = *(const float4*)b;
    float* o = out + (size_t)row * NCLS;
    *(float2*)o       = {v.x + bq.x, v.y + bq.y};
    *(float2*)(o + 2) = {v.z + bq.z, v.w + bq.w};
  } else if (quad == 1) {
    float4 bq = *(const float4*)(b + 4);
    float* o = out + (size_t)row * NCLS + 4;
    *(float2*)o       = {v.x + bq.x, v.y + bq.y};
    *(float2*)(o + 2) = {v.z + bq.z, v.w + bq.w};
  } else if (quad == 2) {
    *(float2*)(out + (size_t)row * NCLS + 8) = {v.x + b[8], v.y + b[9]};
  }
}

// ---- launch --------------------------------------------------------------

extern "C" void kernel_launch(void* const* d_in, const int* in_sizes, int n_in,
                              void* d_out, int out_size, void* d_ws, size_t ws_size,
                              hipStream_t stream) {
  const float* batches = (const float*)d_in[0];  // [16384,512]
  const float* centers = (const float*)d_in[1];  // [2048,512]
  const float* beta    = (const float*)d_in[2];  // [1,2048]
  const float* W       = (const float*)d_in[3];  // [10,2048]
  const float* bias    = (const float*)d_in[4];  // [10]
  float* out = (float*)d_out;                    // [16384,10]

  char* ws = (char*)d_ws;
  u16*  Abf = (u16*)ws;                                   // 16 MiB
  u16*  Bbf = (u16*)(ws + (size_t)M_N * DIM * 2);         // 2 MiB
  float* x2 = (float*)(ws + (size_t)(M_N + K_C) * DIM * 2);
  float* c2 = x2 + M_N;
  u16*  Wpm = (u16*)(c2 + K_C);                           // 64 KiB
  float* partial = (float*)((char*)Wpm + 16 * K_C * 2);   // 16.8 MiB

  prep<<<dim3(NPREP + 32), dim3(256), 0, stream>>>(
      (const float4*)batches, (const float4*)centers, W,
      (ushort4*)Abf, (ushort4*)Bbf, x2, c2, Wpm);
  rbf_main<<<dim3(NBN * NBM), dim3(256), 0, stream>>>(
      Abf, Bbf, x2, c2, beta, Wpm, partial);
  reduce_out<<<dim3(M_N / 64), dim3(256), 0, stream>>>(partial, bias, out);
}